// Round 4
// baseline (145.742 us; speedup 1.0000x reference)
//
#include <hip/hip_runtime.h>

#define NN 8192
#define KDIM 256
#define FDIM 64
#define SLOPEC 0.2f

typedef __attribute__((ext_vector_type(8))) short bf16x8;
typedef __attribute__((ext_vector_type(4))) float f32x4;

__device__ __forceinline__ unsigned short f2bf(float x) {
    union { float f; unsigned u; } v; v.f = x;
    unsigned r = v.u + 0x7FFFu + ((v.u >> 16) & 1u);
    return (unsigned short)(r >> 16);
}

__device__ __forceinline__ float wred64(float v) {
    v += __shfl_xor(v, 1);
    v += __shfl_xor(v, 2);
    v += __shfl_xor(v, 4);
    v += __shfl_xor(v, 8);
    v += __shfl_xor(v, 16);
    v += __shfl_xor(v, 32);
    return v;
}

// Phase 1: Wh = h@W (f32 accum), WhT bf16 [FDIM][NN], f_i = Wh@a[:64], f_j = Wh@a[64:]
__global__ __launch_bounds__(256) void gat_phase1(
    const float* __restrict__ h, const float* __restrict__ W,
    const float* __restrict__ a, unsigned short* __restrict__ whT,
    float* __restrict__ fi, float* __restrict__ fj)
{
    __shared__ unsigned short wht_s[FDIM][20];
    const int tid = threadIdx.x;
    const int f  = tid & 63;
    const int rg = tid >> 6;
    const int i0 = blockIdx.x << 4;

    const float* __restrict__ h0 = h + (size_t)(i0 + rg * 4) * KDIM;
    const float* __restrict__ h1 = h0 + KDIM;
    const float* __restrict__ h2 = h0 + 2 * KDIM;
    const float* __restrict__ h3 = h0 + 3 * KDIM;

    float acc0 = 0.f, acc1 = 0.f, acc2 = 0.f, acc3 = 0.f;
    #pragma unroll 4
    for (int k4 = 0; k4 < KDIM / 4; ++k4) {
        const float4 r0 = *(const float4*)(h0 + k4 * 4);
        const float4 r1 = *(const float4*)(h1 + k4 * 4);
        const float4 r2 = *(const float4*)(h2 + k4 * 4);
        const float4 r3 = *(const float4*)(h3 + k4 * 4);
        const float w0 = W[(k4 * 4 + 0) * FDIM + f];
        const float w1 = W[(k4 * 4 + 1) * FDIM + f];
        const float w2 = W[(k4 * 4 + 2) * FDIM + f];
        const float w3 = W[(k4 * 4 + 3) * FDIM + f];
        acc0 += r0.x * w0 + r0.y * w1 + r0.z * w2 + r0.w * w3;
        acc1 += r1.x * w0 + r1.y * w1 + r1.z * w2 + r1.w * w3;
        acc2 += r2.x * w0 + r2.y * w1 + r2.z * w2 + r2.w * w3;
        acc3 += r3.x * w0 + r3.y * w1 + r3.z * w2 + r3.w * w3;
    }

    const int r0i = rg * 4;
    wht_s[f][r0i + 0] = f2bf(acc0);
    wht_s[f][r0i + 1] = f2bf(acc1);
    wht_s[f][r0i + 2] = f2bf(acc2);
    wht_s[f][r0i + 3] = f2bf(acc3);

    const float aL = a[f];
    const float aR = a[FDIM + f];
    float s;
    s = wred64(acc0 * aL); if (f == 0) fi[i0 + r0i + 0] = s;
    s = wred64(acc1 * aL); if (f == 0) fi[i0 + r0i + 1] = s;
    s = wred64(acc2 * aL); if (f == 0) fi[i0 + r0i + 2] = s;
    s = wred64(acc3 * aL); if (f == 0) fi[i0 + r0i + 3] = s;
    s = wred64(acc0 * aR); if (f == 0) fj[i0 + r0i + 0] = s;
    s = wred64(acc1 * aR); if (f == 0) fj[i0 + r0i + 1] = s;
    s = wred64(acc2 * aR); if (f == 0) fj[i0 + r0i + 2] = s;
    s = wred64(acc3 * aR); if (f == 0) fj[i0 + r0i + 3] = s;

    __syncthreads();
    const int fr = tid >> 2, c = tid & 3;
    ushort4 v;
    v.x = wht_s[fr][c * 4 + 0];
    v.y = wht_s[fr][c * 4 + 1];
    v.z = wht_s[fr][c * 4 + 2];
    v.w = wht_s[fr][c * 4 + 3];
    *(ushort4*)(whT + (size_t)fr * NN + i0 + c * 4) = v;
}

// Phase 2a: pure adj stream -> bitmask. One wave per row; sequential 256B reads,
// ballot-compress 64 ints -> 2 words. No fast loads share this wave's vmcnt queue.
__global__ __launch_bounds__(256) void gat_adjmask(
    const int* __restrict__ adj, unsigned* __restrict__ mask)
{
    const int tid = threadIdx.x;
    const int l  = tid & 63;
    const int gw = (blockIdx.x << 2) | (tid >> 6);      // wave id == row
    const int* __restrict__ row = adj + (size_t)gw * NN;
    unsigned* __restrict__ mrow = mask + (size_t)gw * (NN / 32);

    #pragma unroll 1
    for (int t0 = 0; t0 < 128; t0 += 8) {
        int v[8];
        #pragma unroll
        for (int k = 0; k < 8; ++k)
            v[k] = row[(t0 + k) * 64 + l];
        #pragma unroll
        for (int k = 0; k < 8; ++k) {
            const unsigned long long m = __ballot(v[k] > 0);
            const unsigned half = (l & 1) ? (unsigned)(m >> 32) : (unsigned)m;
            if (l < 2) mrow[2 * (t0 + k) + l] = half;
        }
    }
}

// Phase 2b: 512 thr (8 waves), 16 rows/block; wave w walks windows tw = w+8s.
// All loads (mask word, fj LDS, whT b-frags) are L2-class; no barriers in main loop.
__global__ __launch_bounds__(512, 4) void gat_phase2(
    const unsigned* __restrict__ mask, const unsigned short* __restrict__ whT,
    const float* __restrict__ fi, const float* __restrict__ fjg,
    float* __restrict__ out)
{
    __shared__ float fj_s[NN];        // 32 KB; reused as red[8][16][64] in epilogue
    __shared__ float zred[128];

    const int tid = threadIdx.x;
    const int w  = tid >> 6;   // 0..7
    const int l  = tid & 63;
    const int li = l & 15;     // MFMA A row
    const int q  = l >> 4;     // k-quarter
    const int qo = q * 8;
    const int i0 = blockIdx.x << 4;

    for (int t4 = tid; t4 < NN / 4; t4 += 512)
        ((float4*)fj_s)[t4] = ((const float4*)fjg)[t4];
    __syncthreads();

    const float f_i = fi[i0 + li];
    const unsigned* __restrict__ mrow = mask + (size_t)(i0 + li) * (NN / 32);
    const unsigned short* __restrict__ wrow0 = whT + (size_t)(0 * 16 + li) * NN;
    const unsigned short* __restrict__ wrow1 = whT + (size_t)(1 * 16 + li) * NN;
    const unsigned short* __restrict__ wrow2 = whT + (size_t)(2 * 16 + li) * NN;
    const unsigned short* __restrict__ wrow3 = whT + (size_t)(3 * 16 + li) * NN;

    f32x4 acc0 = {0.f, 0.f, 0.f, 0.f};
    f32x4 acc1 = {0.f, 0.f, 0.f, 0.f};
    f32x4 acc2 = {0.f, 0.f, 0.f, 0.f};
    f32x4 acc3 = {0.f, 0.f, 0.f, 0.f};
    float z = 0.f;

    #pragma unroll 4
    for (int tw = w; tw < NN / 32; tw += 8) {
        const int jg = tw * 32 + qo;
        const unsigned mq = mrow[tw] >> qo;       // 8 mask bits for this lane
        const float4 fj0 = *(const float4*)(fj_s + jg);
        const float4 fj1 = *(const float4*)(fj_s + jg + 4);
        const bf16x8 b0 = *(const bf16x8*)(wrow0 + jg);
        const bf16x8 b1 = *(const bf16x8*)(wrow1 + jg);
        const bf16x8 b2 = *(const bf16x8*)(wrow2 + jg);
        const bf16x8 b3 = *(const bf16x8*)(wrow3 + jg);
        float e0 = f_i + fj0.x; e0 = fmaxf(e0, SLOPEC * e0);
        float e1 = f_i + fj0.y; e1 = fmaxf(e1, SLOPEC * e1);
        float e2 = f_i + fj0.z; e2 = fmaxf(e2, SLOPEC * e2);
        float e3 = f_i + fj0.w; e3 = fmaxf(e3, SLOPEC * e3);
        float e4 = f_i + fj1.x; e4 = fmaxf(e4, SLOPEC * e4);
        float e5 = f_i + fj1.y; e5 = fmaxf(e5, SLOPEC * e5);
        float e6 = f_i + fj1.z; e6 = fmaxf(e6, SLOPEC * e6);
        float e7 = f_i + fj1.w; e7 = fmaxf(e7, SLOPEC * e7);
        const float p0 = (mq &   1u) ? __expf(e0) : 0.f;
        const float p1 = (mq &   2u) ? __expf(e1) : 0.f;
        const float p2 = (mq &   4u) ? __expf(e2) : 0.f;
        const float p3 = (mq &   8u) ? __expf(e3) : 0.f;
        const float p4 = (mq &  16u) ? __expf(e4) : 0.f;
        const float p5 = (mq &  32u) ? __expf(e5) : 0.f;
        const float p6 = (mq &  64u) ? __expf(e6) : 0.f;
        const float p7 = (mq & 128u) ? __expf(e7) : 0.f;
        z += ((p0 + p1) + (p2 + p3)) + ((p4 + p5) + (p6 + p7));
        bf16x8 afrag;
        afrag[0] = (short)f2bf(p0);
        afrag[1] = (short)f2bf(p1);
        afrag[2] = (short)f2bf(p2);
        afrag[3] = (short)f2bf(p3);
        afrag[4] = (short)f2bf(p4);
        afrag[5] = (short)f2bf(p5);
        afrag[6] = (short)f2bf(p6);
        afrag[7] = (short)f2bf(p7);
        acc0 = __builtin_amdgcn_mfma_f32_16x16x32_bf16(afrag, b0, acc0, 0, 0, 0);
        acc1 = __builtin_amdgcn_mfma_f32_16x16x32_bf16(afrag, b1, acc1, 0, 0, 0);
        acc2 = __builtin_amdgcn_mfma_f32_16x16x32_bf16(afrag, b2, acc2, 0, 0, 0);
        acc3 = __builtin_amdgcn_mfma_f32_16x16x32_bf16(afrag, b3, acc3, 0, 0, 0);
    }

    // epilogue: cross-wave reduce + normalize (red reuses fj_s)
    __syncthreads();
    float* red = fj_s;
    #pragma unroll
    for (int r = 0; r < 4; ++r) {
        red[(w * 16 + q * 4 + r) * 64 + 0 * 16 + li] = acc0[r];
        red[(w * 16 + q * 4 + r) * 64 + 1 * 16 + li] = acc1[r];
        red[(w * 16 + q * 4 + r) * 64 + 2 * 16 + li] = acc2[r];
        red[(w * 16 + q * 4 + r) * 64 + 3 * 16 + li] = acc3[r];
    }
    z += __shfl_xor(z, 16);
    z += __shfl_xor(z, 32);
    if (q == 0) zred[w * 16 + li] = z;
    __syncthreads();

    const int f  = tid & 63;
    const int ig = tid >> 6;
    #pragma unroll
    for (int cc = 0; cc < 2; ++cc) {
        const int i = cc * 8 + ig;
        const float v = ((red[(0 * 16 + i) * 64 + f] + red[(1 * 16 + i) * 64 + f])
                       + (red[(2 * 16 + i) * 64 + f] + red[(3 * 16 + i) * 64 + f]))
                      + ((red[(4 * 16 + i) * 64 + f] + red[(5 * 16 + i) * 64 + f])
                       + (red[(6 * 16 + i) * 64 + f] + red[(7 * 16 + i) * 64 + f]));
        const float zz = ((zred[0 * 16 + i] + zred[1 * 16 + i]) + (zred[2 * 16 + i] + zred[3 * 16 + i]))
                       + ((zred[4 * 16 + i] + zred[5 * 16 + i]) + (zred[6 * 16 + i] + zred[7 * 16 + i]));
        out[(size_t)(i0 + i) * FDIM + f] = v / zz;
    }
}

extern "C" void kernel_launch(void* const* d_in, const int* in_sizes, int n_in,
                              void* d_out, int out_size, void* d_ws, size_t ws_size,
                              hipStream_t stream) {
    const float* h   = (const float*)d_in[0];
    const int*   adj = (const int*)d_in[1];
    const float* W   = (const float*)d_in[2];
    const float* a   = (const float*)d_in[3];
    float* out = (float*)d_out;

    unsigned short* whT = (unsigned short*)d_ws;                        // 1 MB @ 0
    float* fi = (float*)((char*)d_ws + (size_t)NN * FDIM * 2);          // 32 KB @ 1MB
    float* fj = fi + NN;                                                // 32 KB
    unsigned* mask = (unsigned*)((char*)d_ws + (2u << 20));             // 8 MB @ 2MB

    gat_phase1<<<NN / 16, 256, 0, stream>>>(h, W, a, whT, fi, fj);
    gat_adjmask<<<NN / 4, 256, 0, stream>>>(adj, mask);
    gat_phase2<<<NN / 16, 512, 0, stream>>>(mask, whT, fi, fj, out);
}

// Round 5
// 107.230 us; speedup vs baseline: 1.3592x; 1.3592x over previous
//
#include <hip/hip_runtime.h>

#define NN 8192
#define KDIM 256
#define FDIM 64
#define SLOPEC 0.2f

typedef __attribute__((ext_vector_type(8))) short bf16x8;
typedef __attribute__((ext_vector_type(4))) float f32x4;

__device__ __forceinline__ unsigned short f2bf(float x) {
    union { float f; unsigned u; } v; v.f = x;
    unsigned r = v.u + 0x7FFFu + ((v.u >> 16) & 1u);
    return (unsigned short)(r >> 16);
}

__device__ __forceinline__ float wred64(float v) {
    v += __shfl_xor(v, 1);
    v += __shfl_xor(v, 2);
    v += __shfl_xor(v, 4);
    v += __shfl_xor(v, 8);
    v += __shfl_xor(v, 16);
    v += __shfl_xor(v, 32);
    return v;
}

// Phase 1: Wh = h@W (f32 accum); emit whT in MFMA-fragment order:
// frag block for window t (32 cols): byte offset t*4096 + b*1024 + lane*16,
// lane l holds Wh[t*32 + (l>>4)*8 + e][b*16 + (l&15)]  (e = 0..7, bf16).
// Also f_i = Wh@a[:64], f_j = Wh@a[64:].
__global__ __launch_bounds__(256) void gat_phase1(
    const float* __restrict__ h, const float* __restrict__ W,
    const float* __restrict__ a, unsigned short* __restrict__ wfrag,
    float* __restrict__ fi, float* __restrict__ fj)
{
    __shared__ unsigned short wht_s[FDIM][20];   // [feature][local col]
    const int tid = threadIdx.x;
    const int f  = tid & 63;
    const int rg = tid >> 6;
    const int i0 = blockIdx.x << 4;

    const float* __restrict__ h0 = h + (size_t)(i0 + rg * 4) * KDIM;
    const float* __restrict__ h1 = h0 + KDIM;
    const float* __restrict__ h2 = h0 + 2 * KDIM;
    const float* __restrict__ h3 = h0 + 3 * KDIM;

    float acc0 = 0.f, acc1 = 0.f, acc2 = 0.f, acc3 = 0.f;
    #pragma unroll 4
    for (int k4 = 0; k4 < KDIM / 4; ++k4) {
        const float4 r0 = *(const float4*)(h0 + k4 * 4);
        const float4 r1 = *(const float4*)(h1 + k4 * 4);
        const float4 r2 = *(const float4*)(h2 + k4 * 4);
        const float4 r3 = *(const float4*)(h3 + k4 * 4);
        const float w0 = W[(k4 * 4 + 0) * FDIM + f];
        const float w1 = W[(k4 * 4 + 1) * FDIM + f];
        const float w2 = W[(k4 * 4 + 2) * FDIM + f];
        const float w3 = W[(k4 * 4 + 3) * FDIM + f];
        acc0 += r0.x * w0 + r0.y * w1 + r0.z * w2 + r0.w * w3;
        acc1 += r1.x * w0 + r1.y * w1 + r1.z * w2 + r1.w * w3;
        acc2 += r2.x * w0 + r2.y * w1 + r2.z * w2 + r2.w * w3;
        acc3 += r3.x * w0 + r3.y * w1 + r3.z * w2 + r3.w * w3;
    }

    const int r0i = rg * 4;
    wht_s[f][r0i + 0] = f2bf(acc0);
    wht_s[f][r0i + 1] = f2bf(acc1);
    wht_s[f][r0i + 2] = f2bf(acc2);
    wht_s[f][r0i + 3] = f2bf(acc3);

    const float aL = a[f];
    const float aR = a[FDIM + f];
    float s;
    s = wred64(acc0 * aL); if (f == 0) fi[i0 + r0i + 0] = s;
    s = wred64(acc1 * aL); if (f == 0) fi[i0 + r0i + 1] = s;
    s = wred64(acc2 * aL); if (f == 0) fi[i0 + r0i + 2] = s;
    s = wred64(acc3 * aL); if (f == 0) fi[i0 + r0i + 3] = s;
    s = wred64(acc0 * aR); if (f == 0) fj[i0 + r0i + 0] = s;
    s = wred64(acc1 * aR); if (f == 0) fj[i0 + r0i + 1] = s;
    s = wred64(acc2 * aR); if (f == 0) fj[i0 + r0i + 2] = s;
    s = wred64(acc3 * aR); if (f == 0) fj[i0 + r0i + 3] = s;

    __syncthreads();
    // fragment-order store: this block covers half h of window t
    if (tid < 128) {
        const int li2 = tid & 15;
        const int q2  = (tid >> 4) & 1;   // local col group (0: cols 0-7, 1: cols 8-15)
        const int b   = tid >> 5;         // feature band 0..3
        const int t   = i0 >> 5;
        const int hh  = (i0 >> 4) & 1;
        const int feat = b * 16 + li2;
        const ushort4 lo = *(const ushort4*)&wht_s[feat][q2 * 8];
        const ushort4 hi = *(const ushort4*)&wht_s[feat][q2 * 8 + 4];
        const int lg = (hh * 2 + q2) * 16 + li2;   // global lane in window
        unsigned short* dst = wfrag + (size_t)t * 2048 + b * 512 + lg * 8;
        *(ushort4*)(dst)     = lo;
        *(ushort4*)(dst + 4) = hi;
    }
}

// Phase 2a: pure adj stream -> row-major bitmask. One wave per row; int4 loads
// (1 KB/instr), 8-deep in flight; shfl-xor nibble pack; 32 B contiguous writes.
__global__ __launch_bounds__(256) void gat_adjmask(
    const int* __restrict__ adj, unsigned* __restrict__ mask)
{
    const int tid = threadIdx.x;
    const int l  = tid & 63;
    const int gw = (blockIdx.x << 2) | (tid >> 6);          // row
    const int* __restrict__ row = adj + (size_t)gw * NN;
    unsigned* __restrict__ mrow = mask + (size_t)gw * (NN / 32);

    const int wsel = (l & 7) * 4;
    #pragma unroll 1
    for (int base = 0; base < 32; base += 8) {
        int4 v[8];
        #pragma unroll
        for (int k = 0; k < 8; ++k)
            v[k] = *(const int4*)(row + (base + k) * 256 + l * 4);
        #pragma unroll
        for (int k = 0; k < 8; ++k) {
            unsigned nib = (unsigned)(v[k].x > 0) | ((unsigned)(v[k].y > 0) << 1)
                         | ((unsigned)(v[k].z > 0) << 2) | ((unsigned)(v[k].w > 0) << 3);
            unsigned part = nib << wsel;
            part |= __shfl_xor(part, 1);
            part |= __shfl_xor(part, 2);
            part |= __shfl_xor(part, 4);
            if ((l & 7) == 0) mrow[(base + k) * 8 + (l >> 3)] = part;
        }
    }
}

// Phase 2b: 512 thr (8 waves), 16 rows/block; wave w walks windows tw = w+8s.
// B-fragments read as contiguous 1 KB bursts from wfrag (sequential 4 KB/step).
__global__ __launch_bounds__(512, 4) void gat_phase2(
    const unsigned* __restrict__ mask, const unsigned short* __restrict__ wfrag,
    const float* __restrict__ fi, const float* __restrict__ fjg,
    float* __restrict__ out)
{
    __shared__ float fj_s[NN];        // 32 KB; reused as red[8][16][64] in epilogue
    __shared__ float zred[128];

    const int tid = threadIdx.x;
    const int w  = tid >> 6;   // 0..7
    const int l  = tid & 63;
    const int li = l & 15;     // MFMA A row
    const int q  = l >> 4;     // k-quarter
    const int qo = q * 8;
    const int i0 = blockIdx.x << 4;

    for (int t4 = tid; t4 < NN / 4; t4 += 512)
        ((float4*)fj_s)[t4] = ((const float4*)fjg)[t4];
    __syncthreads();

    const float f_i = fi[i0 + li];
    const unsigned* __restrict__ mrow = mask + (size_t)(i0 + li) * (NN / 32);
    const unsigned short* __restrict__ wf = wfrag + l * 8;   // lane base

    f32x4 acc0 = {0.f, 0.f, 0.f, 0.f};
    f32x4 acc1 = {0.f, 0.f, 0.f, 0.f};
    f32x4 acc2 = {0.f, 0.f, 0.f, 0.f};
    f32x4 acc3 = {0.f, 0.f, 0.f, 0.f};
    float z = 0.f;

    #pragma unroll 4
    for (int tw = w; tw < NN / 32; tw += 8) {
        const int jg = tw * 32 + qo;
        const unsigned mq = mrow[tw] >> qo;       // 8 mask bits for this lane
        const float4 fj0 = *(const float4*)(fj_s + jg);
        const float4 fj1 = *(const float4*)(fj_s + jg + 4);
        const unsigned short* wt = wf + (size_t)tw * 2048;
        const bf16x8 b0 = *(const bf16x8*)(wt);
        const bf16x8 b1 = *(const bf16x8*)(wt + 512);
        const bf16x8 b2 = *(const bf16x8*)(wt + 1024);
        const bf16x8 b3 = *(const bf16x8*)(wt + 1536);
        float e0 = f_i + fj0.x; e0 = fmaxf(e0, SLOPEC * e0);
        float e1 = f_i + fj0.y; e1 = fmaxf(e1, SLOPEC * e1);
        float e2 = f_i + fj0.z; e2 = fmaxf(e2, SLOPEC * e2);
        float e3 = f_i + fj0.w; e3 = fmaxf(e3, SLOPEC * e3);
        float e4 = f_i + fj1.x; e4 = fmaxf(e4, SLOPEC * e4);
        float e5 = f_i + fj1.y; e5 = fmaxf(e5, SLOPEC * e5);
        float e6 = f_i + fj1.z; e6 = fmaxf(e6, SLOPEC * e6);
        float e7 = f_i + fj1.w; e7 = fmaxf(e7, SLOPEC * e7);
        const float p0 = (mq &   1u) ? __expf(e0) : 0.f;
        const float p1 = (mq &   2u) ? __expf(e1) : 0.f;
        const float p2 = (mq &   4u) ? __expf(e2) : 0.f;
        const float p3 = (mq &   8u) ? __expf(e3) : 0.f;
        const float p4 = (mq &  16u) ? __expf(e4) : 0.f;
        const float p5 = (mq &  32u) ? __expf(e5) : 0.f;
        const float p6 = (mq &  64u) ? __expf(e6) : 0.f;
        const float p7 = (mq & 128u) ? __expf(e7) : 0.f;
        z += ((p0 + p1) + (p2 + p3)) + ((p4 + p5) + (p6 + p7));
        bf16x8 afrag;
        afrag[0] = (short)f2bf(p0);
        afrag[1] = (short)f2bf(p1);
        afrag[2] = (short)f2bf(p2);
        afrag[3] = (short)f2bf(p3);
        afrag[4] = (short)f2bf(p4);
        afrag[5] = (short)f2bf(p5);
        afrag[6] = (short)f2bf(p6);
        afrag[7] = (short)f2bf(p7);
        acc0 = __builtin_amdgcn_mfma_f32_16x16x32_bf16(afrag, b0, acc0, 0, 0, 0);
        acc1 = __builtin_amdgcn_mfma_f32_16x16x32_bf16(afrag, b1, acc1, 0, 0, 0);
        acc2 = __builtin_amdgcn_mfma_f32_16x16x32_bf16(afrag, b2, acc2, 0, 0, 0);
        acc3 = __builtin_amdgcn_mfma_f32_16x16x32_bf16(afrag, b3, acc3, 0, 0, 0);
    }

    // epilogue: cross-wave reduce + normalize (red reuses fj_s)
    __syncthreads();
    float* red = fj_s;
    #pragma unroll
    for (int r = 0; r < 4; ++r) {
        red[(w * 16 + q * 4 + r) * 64 + 0 * 16 + li] = acc0[r];
        red[(w * 16 + q * 4 + r) * 64 + 1 * 16 + li] = acc1[r];
        red[(w * 16 + q * 4 + r) * 64 + 2 * 16 + li] = acc2[r];
        red[(w * 16 + q * 4 + r) * 64 + 3 * 16 + li] = acc3[r];
    }
    z += __shfl_xor(z, 16);
    z += __shfl_xor(z, 32);
    if (q == 0) zred[w * 16 + li] = z;
    __syncthreads();

    const int f  = tid & 63;
    const int ig = tid >> 6;
    #pragma unroll
    for (int cc = 0; cc < 2; ++cc) {
        const int i = cc * 8 + ig;
        const float v = ((red[(0 * 16 + i) * 64 + f] + red[(1 * 16 + i) * 64 + f])
                       + (red[(2 * 16 + i) * 64 + f] + red[(3 * 16 + i) * 64 + f]))
                      + ((red[(4 * 16 + i) * 64 + f] + red[(5 * 16 + i) * 64 + f])
                       + (red[(6 * 16 + i) * 64 + f] + red[(7 * 16 + i) * 64 + f]));
        const float zz = ((zred[0 * 16 + i] + zred[1 * 16 + i]) + (zred[2 * 16 + i] + zred[3 * 16 + i]))
                       + ((zred[4 * 16 + i] + zred[5 * 16 + i]) + (zred[6 * 16 + i] + zred[7 * 16 + i]));
        out[(size_t)(i0 + i) * FDIM + f] = v / zz;
    }
}

extern "C" void kernel_launch(void* const* d_in, const int* in_sizes, int n_in,
                              void* d_out, int out_size, void* d_ws, size_t ws_size,
                              hipStream_t stream) {
    const float* h   = (const float*)d_in[0];
    const int*   adj = (const int*)d_in[1];
    const float* W   = (const float*)d_in[2];
    const float* a   = (const float*)d_in[3];
    float* out = (float*)d_out;

    unsigned short* wfrag = (unsigned short*)d_ws;                      // 1 MB @ 0 (fragment-order)
    float* fi = (float*)((char*)d_ws + (size_t)NN * FDIM * 2);          // 32 KB @ 1MB
    float* fj = fi + NN;                                                // 32 KB
    unsigned* mask = (unsigned*)((char*)d_ws + (2u << 20));             // 8 MB @ 2MB

    gat_phase1<<<NN / 16, 256, 0, stream>>>(h, W, a, wfrag, fi, fj);
    gat_adjmask<<<NN / 4, 256, 0, stream>>>(adj, mask);
    gat_phase2<<<NN / 16, 512, 0, stream>>>(mask, wfrag, fi, fj, out);
}